// Round 7
// baseline (152.927 us; speedup 1.0000x reference)
//
#include <hip/hip_runtime.h>

namespace {

constexpr int L           = 128;
constexpr int NANG        = 120;
constexpr int SLICE_BYTES = L * L * 4;              // 65536
constexpr int ROW_BYTES   = L * 4;                  // 512
constexpr int PAIR_BYTES  = 2 * ROW_BYTES + 32;     // 1056: 2 rows + 32B bank skew
constexpr int NPAIR       = 8;                      // 6 data pairs + 2 zero pairs (slots 12..15)
constexpr int B_REGION    = NPAIR * PAIR_BYTES;     // 8448 per b
constexpr int STAGE_BUF   = 2 * B_REGION;           // 16896 per buffer

typedef __fp16 f16x2 __attribute__((ext_vector_type(2)));
typedef __fp16 f16x4 __attribute__((ext_vector_type(4)));
typedef float  f32x4 __attribute__((ext_vector_type(4)));

// Block: 512 thr = 8 waves. Tile: 8(x) x 4(y) = 32 points, both b, all 128 z.
// Wave w: b = w&1, zq2 = w>>1 (32-z quarter). Each wave computes BOTH 16-point
// M-tiles (A-fragments differ, B-fragment shared) -> halves LDS B-reads.
// Per angle: D[point][z] += W[point][slot] * Rows[slot][z] via mfma 16x16x16 f16.
__global__ __launch_bounds__(512, 4) void bp_kernel(
    const float* __restrict__ image,   // [2,120,128,128] f32
    const float* __restrict__ angles,  // [120] deg
    float* __restrict__ out)           // [2,128,128,128] f32
{
    __shared__ alignas(16) char  stage[2 * STAGE_BUF];   // 33 KiB, skewed pair layout
    __shared__ alignas(16) uint2 wtab[NANG * 32];        // 30 KiB: [a][p] {w0|w1<<16, s0|s1<<4}
    __shared__ float2 acs[NANG];
    __shared__ int    ari[NANG];                         // rlo | nrows<<8
    __shared__ alignas(16) float nrmtab[32];

    const int tid = threadIdx.x;
    const int yb  = blockIdx.x * 4;
    const int xb  = blockIdx.y * 8;
    const float cx = (L - 1) * 0.5f;

    // ---- Phase 0: per-angle params + tile row range; zero pad pairs; zero norms ----
    if (tid < NANG) {
        const float phi = -angles[tid] * 0.017453292519943295f;
        float s, c;
        sincosf(phi, &s, &c);
        const float X0 = (float)xb - cx,       X1 = (float)(xb + 7) - cx;
        const float Y0 = (float)yb - cx,       Y1 = (float)(yb + 3) - cx;
        const float a00 = -s * X0 + c * Y0 + cx;
        const float a01 = -s * X0 + c * Y1 + cx;
        const float a10 = -s * X1 + c * Y0 + cx;
        const float a11 = -s * X1 + c * Y1 + cx;
        const float symin = fminf(fminf(a00, a01), fminf(a10, a11));
        const float symax = fmaxf(fmaxf(a00, a01), fmaxf(a10, a11));
        const int rlo = min(max((int)floorf(symin) - 1, 0), L - 1);
        const int rhi = min(max((int)floorf(symax) + 2, 0), L - 1);
        acs[tid] = make_float2(c, s);
        ari[tid] = rlo | ((rhi - rlo + 1) << 8);   // nrows <= 12
    }
    if (tid < 32) nrmtab[tid] = 0.f;
    for (int o = tid; o < 528; o += 512) {   // zero pairs 6,7 of each (buf,b): 528 x 16B
        const int pr = o / 66;               // 0..7 = buf(2) x b(2) x padpair(2)
        const int wi = o - pr * 66;
        char* p = &stage[(pr >> 2) * STAGE_BUF + ((pr >> 1) & 1) * B_REGION
                         + (6 + (pr & 1)) * PAIR_BYTES + wi * 16];
        *(float4*)p = make_float4(0.f, 0.f, 0.f, 0.f);
    }
    __syncthreads();

    const int wave  = tid >> 6;
    const int lane  = tid & 63;
    const int quad  = lane >> 4;
    const int lhalf = lane & 15;
    const int b     = wave & 1;
    const int zq2   = wave >> 1;               // 0..3, 32 z's each
    const char* __restrict__ imgc = (const char*)image;

    // stage 12 row-pairs (2 b x 6 pairs) of angle a1 into buffer buf.
    auto stage_fn = [&](int a1, int buf) {
        const int ri  = ari[a1];
        const int rlo = ri & 0xff;
        const int nm1 = (ri >> 8) - 1;
        auto issue = [&](int u) {
            const int bu = (u >= 6) ? 1 : 0;
            const int pp = u - bu * 6;              // pair 0..5
            const int t  = 2 * pp + (lane >> 5);    // lanes 0-31 row0, 32-63 row1
            const int te = min(t, nm1);
            const unsigned goff = (unsigned)(bu * NANG + a1) * SLICE_BYTES
                                + (unsigned)(rlo + te) * ROW_BYTES
                                + (unsigned)(lane & 31) * 16u;
            char* lp = &stage[buf * STAGE_BUF + bu * B_REGION + pp * PAIR_BYTES];
            __builtin_amdgcn_global_load_lds(
                (const __attribute__((address_space(1))) unsigned int*)(imgc + goff),
                (__attribute__((address_space(3))) unsigned int*)lp, 16, 0, 0);
        };
        issue(wave);
        if (wave < 4) issue(8 + wave);
    };

    stage_fn(0, 0);   // overlaps with phase 1 compute

    // ---- Phase 1: per-(point,angle) table entry {f16 w0|w1, slots s0|s1<<4} ----
    for (int e = tid; e < 32 * NANG; e += 512) {
        const int p = e / NANG;
        const int a = e - p * NANG;
        const float2 cs = acs[a];
        const int ri  = ari[a];
        const int rlo = ri & 0xff;
        const float X = (float)(xb + (p >> 2)) - cx;
        const float Y = (float)(yb + (p & 3)) - cx;
        const float sx =  cs.x * X + cs.y * Y + cx;
        const float sy = -cs.y * X + cs.x * Y + cx;
        const float x0f = floorf(sx), y0f = floorf(sy);
        const float wx = sx - x0f,    wy = sy - y0f;
        const int x0 = (int)x0f, y0 = (int)y0f;
        const float mx0 = (x0 >= 0  && x0 <  L)     ? 1.f : 0.f;
        const float mx1 = (x0 >= -1 && x0 <= L - 2) ? 1.f : 0.f;
        const float my0 = (y0 >= 0  && y0 <  L)     ? 1.f : 0.f;
        const float my1 = (y0 >= -1 && y0 <= L - 2) ? 1.f : 0.f;
        const float A   = (1.f - wx) * mx0 + wx * mx1;
        float w0f = (1.f - wy) * my0 * A;
        float w1f = wy * my1 * A;
        const int y0c = min(max(y0, 0), L - 1);
        const int y1c = min(max(y0 + 1, 0), L - 1);
        const int s0  = min(max(y0c - rlo, 0), 11);
        const int s1  = min(max(y1c - rlo, 0), 11);
        // Slot collision (boundary clamp): k==s0 shadows k==s1 in the sparse-A
        // selector -> fold so no weight is dropped.
        if (s0 == s1) { w0f += w1f; w1f = 0.f; }
        f16x2 wh = __builtin_amdgcn_cvt_pkrtz(w0f, w1f);
        uint2 ent;
        ent.x = *reinterpret_cast<unsigned*>(&wh);
        ent.y = (unsigned)(s0 | (s1 << 4));
        wtab[a * 32 + p] = ent;
        atomicAdd(&nrmtab[p], w0f + w1f);
    }
    __syncthreads();   // drains stage(0) + phase-1 tables

    f32x4 acc[2][2] = {};   // [mt][i]

    // A-fragment: A[m=lhalf][k=quad*4+j] = (k==s0)?w0 : (k==s1)?w1 : 0
    auto build_af = [&](uint2 e) -> f16x4 {
        const unsigned s0 = e.y & 15u, s1 = (e.y >> 4) & 15u;
        const unsigned lo = e.x & 0xffffu, hi = e.x >> 16;
        unsigned ea[4];
#pragma unroll
        for (int j = 0; j < 4; ++j) {
            const unsigned k = (unsigned)(quad * 4 + j);
            ea[j] = (k == s0) ? lo : ((k == s1) ? hi : 0u);
        }
        union { unsigned u[2]; f16x4 v; } af;
        af.u[0] = ea[0] | (ea[1] << 16);
        af.u[1] = ea[2] | (ea[3] << 16);
        return af.v;
    };

    auto body = [&](int a, int bufR) {
        if (a + 1 < NANG) stage_fn(a + 1, bufR ^ 1);

        const uint2* wrow = &wtab[a * 32];
        const f16x4 af0 = build_af(wrow[lhalf]);        // mt=0 (ds_read_b64 broadcast)
        const f16x4 af1 = build_af(wrow[16 + lhalf]);   // mt=1

        // quad q reads slots 4q..4q+3 = pairs 2q,2q+1; skewed pitch -> 2-way banks (free)
        const char* breg = stage + bufR * STAGE_BUF + b * B_REGION + quad * (2 * PAIR_BYTES);
#pragma unroll
        for (int i = 0; i < 2; ++i) {
            const int zo = ((zq2 * 2 + i) * 16 + lhalf) * 4;
            const float r0 = *(const float*)(breg + zo);                    // slot 4q
            const float r1 = *(const float*)(breg + zo + ROW_BYTES);        // slot 4q+1
            const float r2 = *(const float*)(breg + zo + PAIR_BYTES);       // slot 4q+2
            const float r3 = *(const float*)(breg + zo + PAIR_BYTES + ROW_BYTES); // 4q+3
            const f16x2 h01 = __builtin_amdgcn_cvt_pkrtz(r0, r1);
            const f16x2 h23 = __builtin_amdgcn_cvt_pkrtz(r2, r3);
            const f16x4 bf = {h01.x, h01.y, h23.x, h23.y};
            acc[0][i] = __builtin_amdgcn_mfma_f32_16x16x16f16(af0, bf, acc[0][i], 0, 0, 0);
            acc[1][i] = __builtin_amdgcn_mfma_f32_16x16x16f16(af1, bf, acc[1][i], 0, 0, 0);
        }
        __syncthreads();   // staged(a+1) complete + all reads of bufR done
    };

    for (int a = 0; a < NANG; a += 2) {
        body(a, 0);
        body(a + 1, 1);
    }

    // ---- Epilogue: D[row=quad*4+r][col=lhalf], point p = mt*16+quad*4+r ----
#pragma unroll
    for (int mt = 0; mt < 2; ++mt) {
        const float4 nrm4 = *(const float4*)&nrmtab[mt * 16 + quad * 4];
        const float iv[4] = { 1.f / (nrm4.x + 1e-11f), 1.f / (nrm4.y + 1e-11f),
                              1.f / (nrm4.z + 1e-11f), 1.f / (nrm4.w + 1e-11f) };
#pragma unroll
        for (int i = 0; i < 2; ++i) {
            const int z = (zq2 * 2 + i) * 16 + lhalf;
#pragma unroll
            for (int r = 0; r < 4; ++r) {
                const int p = mt * 16 + quad * 4 + r;
                const int x = xb + (p >> 2);
                const int y = yb + (p & 3);
                out[(((size_t)(b * L + x)) * L + y) * L + z] = acc[mt][i][r] * iv[r];
            }
        }
    }
}

} // namespace

extern "C" void kernel_launch(void* const* d_in, const int* in_sizes, int n_in,
                              void* d_out, int out_size, void* d_ws, size_t ws_size,
                              hipStream_t stream) {
    const float* image  = (const float*)d_in[0];
    const float* angles = (const float*)d_in[1];
    float* out = (float*)d_out;
    (void)in_sizes; (void)n_in; (void)out_size; (void)d_ws; (void)ws_size;

    dim3 grid(L / 4, L / 8);   // 32 x 16 = 512 blocks = exactly 2 per CU
    bp_kernel<<<grid, 512, 0, stream>>>(image, angles, out);
}

// Round 8
// 152.681 us; speedup vs baseline: 1.0016x; 1.0016x over previous
//
#include <hip/hip_runtime.h>

namespace {

constexpr int L           = 128;
constexpr int NANG        = 120;
constexpr int SLICE_BYTES = L * L * 4;          // 65536
constexpr int ROW_BYTES   = L * 4;              // 512
constexpr int PAIR_BYTES  = 2 * ROW_BYTES + 32; // 1056: 2 rows + 32B bank skew
constexpr int B_REGION    = 6 * PAIR_BYTES;     // 6336 (slots 0..11 only)
constexpr int STAGE_BUF   = 2 * B_REGION;       // 12672 per buffer (2 b)

typedef __fp16 f16x2 __attribute__((ext_vector_type(2)));
typedef __fp16 f16x4 __attribute__((ext_vector_type(4)));
typedef float  f32x4 __attribute__((ext_vector_type(4)));

// Block: 512 thr = 8 waves. Tile: 8(x) x 4(y) = 32 points, both b, all 128 z.
// Wave w: b = w&1, zq2 = w>>1 (32-z quarter); computes BOTH 16-point M-tiles.
// Pipeline: 3 LDS buffers, stage(a+2) in flight across a RAW s_barrier with
// partial vmcnt (own-loads only) -- no full drain per angle.
__global__ __launch_bounds__(512, 4) void bp_kernel(
    const float* __restrict__ image,   // [2,120,128,128] f32
    const float* __restrict__ angles,  // [120] deg
    float* __restrict__ out)           // [2,128,128,128] f32
{
    __shared__ alignas(16) char  stage[3 * STAGE_BUF];   // 38 KiB
    __shared__ alignas(16) uint2 wtab[NANG * 32];        // 30 KiB: [a][p] {w0|w1<<16, s0}
    __shared__ float2 acs[NANG];
    __shared__ int    ari[NANG];                         // rlo | nrows<<8
    __shared__ alignas(16) float nrmtab[32];

    const int tid = threadIdx.x;
    const int yb  = blockIdx.x * 4;
    const int xb  = blockIdx.y * 8;
    const float cx = (L - 1) * 0.5f;

    // ---- Phase 0: per-angle params + tile row range ----
    if (tid < NANG) {
        const float phi = -angles[tid] * 0.017453292519943295f;
        float s, c;
        sincosf(phi, &s, &c);
        const float X0 = (float)xb - cx,       X1 = (float)(xb + 7) - cx;
        const float Y0 = (float)yb - cx,       Y1 = (float)(yb + 3) - cx;
        const float a00 = -s * X0 + c * Y0 + cx;
        const float a01 = -s * X0 + c * Y1 + cx;
        const float a10 = -s * X1 + c * Y0 + cx;
        const float a11 = -s * X1 + c * Y1 + cx;
        const float symin = fminf(fminf(a00, a01), fminf(a10, a11));
        const float symax = fmaxf(fmaxf(a00, a01), fmaxf(a10, a11));
        const int rlo = min(max((int)floorf(symin) - 1, 0), L - 1);
        const int rhi = min(max((int)floorf(symax) + 2, 0), L - 1);
        acs[tid] = make_float2(c, s);
        ari[tid] = rlo | ((rhi - rlo + 1) << 8);   // nrows <= 12
    }
    if (tid < 32) nrmtab[tid] = 0.f;
    __syncthreads();

    const int wave  = tid >> 6;
    const int lane  = tid & 63;
    const int quad  = lane >> 4;
    const int lhalf = lane & 15;
    const int b     = wave & 1;
    const int zq2   = wave >> 1;               // 0..3, 32 z's each
    const char* __restrict__ imgc = (const char*)image;

    // stage 12 row-pairs (2 b x 6 pairs) of angle a1. waves 0-3: 2 loads, 4-7: 1.
    auto stage_fn = [&](int a1, int buf) {
        const int ri  = ari[a1];
        const int rlo = ri & 0xff;
        const int nm1 = (ri >> 8) - 1;
        auto issue = [&](int u) {
            const int bu = (u >= 6) ? 1 : 0;
            const int pp = u - bu * 6;              // pair 0..5
            const int t  = 2 * pp + (lane >> 5);    // lanes 0-31 row0, 32-63 row1
            const int te = min(t, nm1);
            const unsigned goff = (unsigned)(bu * NANG + a1) * SLICE_BYTES
                                + (unsigned)(rlo + te) * ROW_BYTES
                                + (unsigned)(lane & 31) * 16u;
            char* lp = &stage[buf * STAGE_BUF + bu * B_REGION + pp * PAIR_BYTES];
            __builtin_amdgcn_global_load_lds(
                (const __attribute__((address_space(1))) unsigned int*)(imgc + goff),
                (__attribute__((address_space(3))) unsigned int*)lp, 16, 0, 0);
        };
        issue(wave);
        if (wave < 4) issue(8 + wave);
    };

    stage_fn(0, 0);   // overlaps with phase 1 compute

    // ---- Phase 1: per-(point,angle) entry {f16 w0|w1, s0}; s1 == s0+1 by construction ----
    for (int e = tid; e < 32 * NANG; e += 512) {
        const int p = e / NANG;
        const int a = e - p * NANG;
        const float2 cs = acs[a];
        const int rlo = ari[a] & 0xff;
        const float X = (float)(xb + (p >> 2)) - cx;
        const float Y = (float)(yb + (p & 3)) - cx;
        const float sx =  cs.x * X + cs.y * Y + cx;
        const float sy = -cs.y * X + cs.x * Y + cx;
        const float x0f = floorf(sx), y0f = floorf(sy);
        const float wx = sx - x0f,    wy = sy - y0f;
        const int x0 = (int)x0f, y0 = (int)y0f;
        const float mx0 = (x0 >= 0  && x0 <  L)     ? 1.f : 0.f;
        const float mx1 = (x0 >= -1 && x0 <= L - 2) ? 1.f : 0.f;
        const float my0 = (y0 >= 0  && y0 <  L)     ? 1.f : 0.f;
        const float my1 = (y0 >= -1 && y0 <= L - 2) ? 1.f : 0.f;
        const float A   = (1.f - wx) * mx0 + wx * mx1;
        float w0f = (1.f - wy) * my0 * A;
        float w1f = wy * my1 * A;
        const int y0c = min(max(y0, 0), L - 1);
        const int y1c = min(max(y0 + 1, 0), L - 1);
        const int s0  = min(max(y0c - rlo, 0), 11);
        const int s1  = min(max(y1c - rlo, 0), 11);
        // Boundary clamp collision (s1==s0): fold w1 into w0 (exact: one mask is 0).
        // Afterwards w1's slot is implicitly s0+1 (zero weight there is harmless).
        if (s0 == s1) { w0f += w1f; w1f = 0.f; }
        f16x2 wh = __builtin_amdgcn_cvt_pkrtz(w0f, w1f);
        uint2 ent;
        ent.x = *reinterpret_cast<unsigned*>(&wh);
        ent.y = (unsigned)s0;
        wtab[a * 32 + p] = ent;
        atomicAdd(&nrmtab[p], w0f + w1f);
    }
    __syncthreads();   // full drain (also retires stage(0)) -- once, outside hot loop

    stage_fn(1, 1);    // second pipeline stage in flight

    f32x4 acc[2][2] = {};   // [mt][i]

    // A-fragment: nonzeros at k=s0 (w0), k=s0+1 (w1); element j of quad's 64-bit window.
    auto build_af = [&](uint2 e) -> f16x4 {
        const unsigned s0 = e.y;
        const unsigned t  = s0 & 3u;
        const int      q0 = (int)(s0 >> 2);
        const unsigned long long W = (unsigned long long)e.x << (t * 16u);
        const unsigned spill = (t == 3u) ? (e.x >> 16) : 0u;
        const unsigned long long af64 =
            (quad == q0) ? W : ((quad == q0 + 1) ? (unsigned long long)spill : 0ull);
        union { unsigned long long u; f16x4 v; } c; c.u = af64; return c.v;
    };

    int bufC = 0, bufI = 2;
    for (int a = 0; a < NANG; ++a) {
        // Wait for OWN stage(a) loads only (stage(a+1) may remain in flight),
        // then raw barrier => all waves' stage(a) DMA writes are visible.
        if (a == NANG - 1) {
            asm volatile("s_waitcnt vmcnt(0)" ::: "memory");
        } else if (wave < 4) {
            asm volatile("s_waitcnt vmcnt(2)" ::: "memory");
        } else {
            asm volatile("s_waitcnt vmcnt(1)" ::: "memory");
        }
        asm volatile("s_barrier" ::: "memory");

        if (a + 2 < NANG) stage_fn(a + 2, bufI);   // safe: bufI's readers finished pre-barrier

        const uint2 eA = wtab[a * 32 + lhalf];        // ds_read_b64 broadcast
        const uint2 eB = wtab[a * 32 + 16 + lhalf];
        const f16x4 af0 = build_af(eA);
        const f16x4 af1 = build_af(eB);

        const char* breg = stage + bufC * STAGE_BUF + b * B_REGION;
#pragma unroll
        for (int i = 0; i < 2; ++i) {
            const int zo  = ((zq2 * 2 + i) * 16 + lhalf) * 4;
            const int off = (quad < 3) ? (quad * (2 * PAIR_BYTES) + zo) : 0; // quad3: broadcast (A=0 there)
            const float r0 = *(const float*)(breg + off);                       // slot 4q
            const float r1 = *(const float*)(breg + off + ROW_BYTES);           // slot 4q+1
            const float r2 = *(const float*)(breg + off + PAIR_BYTES);          // slot 4q+2
            const float r3 = *(const float*)(breg + off + PAIR_BYTES + ROW_BYTES);
            const f16x2 h01 = __builtin_amdgcn_cvt_pkrtz(r0, r1);
            const f16x2 h23 = __builtin_amdgcn_cvt_pkrtz(r2, r3);
            const f16x4 bf = {h01.x, h01.y, h23.x, h23.y};
            acc[0][i] = __builtin_amdgcn_mfma_f32_16x16x16f16(af0, bf, acc[0][i], 0, 0, 0);
            acc[1][i] = __builtin_amdgcn_mfma_f32_16x16x16f16(af1, bf, acc[1][i], 0, 0, 0);
        }

        bufC = (bufC == 2) ? 0 : bufC + 1;
        bufI = (bufI == 2) ? 0 : bufI + 1;
    }

    // ---- Epilogue: D[row=quad*4+r][col=lhalf], point p = mt*16+quad*4+r ----
#pragma unroll
    for (int mt = 0; mt < 2; ++mt) {
        const float4 nrm4 = *(const float4*)&nrmtab[mt * 16 + quad * 4];
        const float iv[4] = { 1.f / (nrm4.x + 1e-11f), 1.f / (nrm4.y + 1e-11f),
                              1.f / (nrm4.z + 1e-11f), 1.f / (nrm4.w + 1e-11f) };
#pragma unroll
        for (int i = 0; i < 2; ++i) {
            const int z = (zq2 * 2 + i) * 16 + lhalf;
#pragma unroll
            for (int r = 0; r < 4; ++r) {
                const int p = mt * 16 + quad * 4 + r;
                const int x = xb + (p >> 2);
                const int y = yb + (p & 3);
                out[(((size_t)(b * L + x)) * L + y) * L + z] = acc[mt][i][r] * iv[r];
            }
        }
    }
}

} // namespace

extern "C" void kernel_launch(void* const* d_in, const int* in_sizes, int n_in,
                              void* d_out, int out_size, void* d_ws, size_t ws_size,
                              hipStream_t stream) {
    const float* image  = (const float*)d_in[0];
    const float* angles = (const float*)d_in[1];
    float* out = (float*)d_out;
    (void)in_sizes; (void)n_in; (void)out_size; (void)d_ws; (void)ws_size;

    dim3 grid(L / 4, L / 8);   // 32 x 16 = 512 blocks = exactly 2 per CU
    bp_kernel<<<grid, 512, 0, stream>>>(image, angles, out);
}

// Round 9
// 145.890 us; speedup vs baseline: 1.0482x; 1.0465x over previous
//
#include <hip/hip_runtime.h>

namespace {

constexpr int L           = 128;
constexpr int NANG        = 120;
constexpr int SLICE_BYTES = L * L * 4;   // 65536 = 1<<16
constexpr int ROW_BYTES   = L * 4;       // 512

typedef __fp16 f16x2 __attribute__((ext_vector_type(2)));
typedef __fp16 f16x4 __attribute__((ext_vector_type(4)));
typedef float  f32x4 __attribute__((ext_vector_type(4)));

// Block: 512 thr = 8 waves. Tile: 8(x) x 4(y) = 32 points, both b, all 128 z.
// Wave w: b = w&1, zq2 = w>>1 (32-z quarter); computes BOTH 16-point M-tiles.
// Per angle: D[point][z] += W[point][slot] * image[b][a][rlo+slot][z] via
// mfma 16x16x16 f16, B-fragments loaded DIRECTLY from global (L1/L2-hot) --
// no staging, no barriers in the main loop.
__global__ __launch_bounds__(512, 4) void bp_kernel(
    const float* __restrict__ image,   // [2,120,128,128] f32
    const float* __restrict__ angles,  // [120] deg
    float* __restrict__ out)           // [2,128,128,128] f32
{
    __shared__ alignas(16) uint2 wtab[NANG * 32];  // 30 KiB: [a][p] {w0|w1<<16, s0}
    __shared__ float2   acs[NANG];
    __shared__ unsigned arlo[NANG];                // per-angle first row
    __shared__ alignas(16) float nrmtab[32];

    const int tid = threadIdx.x;
    const int yb  = blockIdx.x * 4;
    const int xb  = blockIdx.y * 8;
    const float cx = (L - 1) * 0.5f;

    // ---- Phase 0: per-angle rotation params + tile row floor ----
    if (tid < NANG) {
        const float phi = -angles[tid] * 0.017453292519943295f;
        float s, c;
        sincosf(phi, &s, &c);
        const float X0 = (float)xb - cx,       X1 = (float)(xb + 7) - cx;
        const float Y0 = (float)yb - cx,       Y1 = (float)(yb + 3) - cx;
        const float a00 = -s * X0 + c * Y0 + cx;
        const float a01 = -s * X0 + c * Y1 + cx;
        const float a10 = -s * X1 + c * Y0 + cx;
        const float a11 = -s * X1 + c * Y1 + cx;
        const float symin = fminf(fminf(a00, a01), fminf(a10, a11));
        acs[tid]  = make_float2(c, s);
        arlo[tid] = (unsigned)min(max((int)floorf(symin) - 1, 0), L - 1); // nrows <= 12 from here
    }
    if (tid < 32) nrmtab[tid] = 0.f;
    __syncthreads();

    // ---- Phase 1: per-(point,angle) entry {f16 w0|w1, s0}; s1 == s0+1 implicit ----
    for (int e = tid; e < 32 * NANG; e += 512) {
        const int p = e / NANG;
        const int a = e - p * NANG;
        const float2 cs = acs[a];
        const int rlo = (int)arlo[a];
        const float X = (float)(xb + (p >> 2)) - cx;
        const float Y = (float)(yb + (p & 3)) - cx;
        const float sx =  cs.x * X + cs.y * Y + cx;
        const float sy = -cs.y * X + cs.x * Y + cx;
        const float x0f = floorf(sx), y0f = floorf(sy);
        const float wx = sx - x0f,    wy = sy - y0f;
        const int x0 = (int)x0f, y0 = (int)y0f;
        const float mx0 = (x0 >= 0  && x0 <  L)     ? 1.f : 0.f;
        const float mx1 = (x0 >= -1 && x0 <= L - 2) ? 1.f : 0.f;
        const float my0 = (y0 >= 0  && y0 <  L)     ? 1.f : 0.f;
        const float my1 = (y0 >= -1 && y0 <= L - 2) ? 1.f : 0.f;
        const float A   = (1.f - wx) * mx0 + wx * mx1;
        float w0f = (1.f - wy) * my0 * A;
        float w1f = wy * my1 * A;
        const int y0c = min(max(y0, 0), L - 1);
        const int y1c = min(max(y0 + 1, 0), L - 1);
        const int s0  = min(max(y0c - rlo, 0), 11);
        const int s1  = min(max(y1c - rlo, 0), 11);
        // Boundary clamp collision (s1==s0): fold w1 into w0 (exact: one mask is 0).
        if (s0 == s1) { w0f += w1f; w1f = 0.f; }
        f16x2 wh = __builtin_amdgcn_cvt_pkrtz(w0f, w1f);
        uint2 ent;
        ent.x = *reinterpret_cast<unsigned*>(&wh);
        ent.y = (unsigned)s0;
        wtab[a * 32 + p] = ent;
        atomicAdd(&nrmtab[p], w0f + w1f);
    }
    __syncthreads();   // the ONLY barrier before the epilogue

    const int wave  = tid >> 6;
    const int lane  = tid & 63;
    const int quad  = lane >> 4;
    const int lhalf = lane & 15;
    const int b     = wave & 1;
    const int zq2   = wave >> 1;               // 0..3, 32 z's each
    const char* __restrict__ imgc = (const char*)image;

    const unsigned bbase = (unsigned)(b * NANG) * SLICE_BYTES;
    const unsigned zoff0 = (unsigned)((zq2 * 2) * 16 + lhalf) * 4u;   // i=0; i=1 is +64B

    f32x4 acc[2][2] = {};   // [mt][i]

    // A-fragment: nonzeros at k=s0 (w0), k=s0+1 (w1); element j of quad's 64-bit window.
    auto build_af = [&](uint2 e) -> f16x4 {
        const unsigned s0 = e.y;
        const unsigned t  = s0 & 3u;
        const int      q0 = (int)(s0 >> 2);
        const unsigned long long W = (unsigned long long)e.x << (t * 16u);
        const unsigned spill = (t == 3u) ? (e.x >> 16) : 0u;
        const unsigned long long af64 =
            (quad == q0) ? W : ((quad == q0 + 1) ? (unsigned long long)spill : 0ull);
        union { unsigned long long u; f16x4 v; } c; c.u = af64; return c.v;
    };

#pragma unroll 2
    for (int a = 0; a < NANG; ++a) {
        const uint2 eA = wtab[a * 32 + lhalf];        // ds_read_b64 broadcast
        const uint2 eB = wtab[a * 32 + 16 + lhalf];
        const unsigned rlo = arlo[a];
        const f16x4 af0 = build_af(eA);
        const f16x4 af1 = build_af(eB);

        // 4 row addresses for this quad (slots 4q..4q+3). Per-row clamp to the
        // slice end: clamped rows provably have A=0 (nonzero-A slots satisfy
        // rlo+k <= 127), clamp only prevents OOB reads past the image.
        const unsigned sbase = bbase + ((unsigned)a << 16);
        unsigned ro[4];
#pragma unroll
        for (int j = 0; j < 4; ++j)
            ro[j] = sbase + min(rlo + (unsigned)(4 * quad + j), 127u) * ROW_BYTES + zoff0;

#pragma unroll
        for (int i = 0; i < 2; ++i) {
            const unsigned zi = (unsigned)(i * 64);   // folds into the 13-bit inst offset
            const float r0 = *(const float*)(imgc + (ro[0] + zi));
            const float r1 = *(const float*)(imgc + (ro[1] + zi));
            const float r2 = *(const float*)(imgc + (ro[2] + zi));
            const float r3 = *(const float*)(imgc + (ro[3] + zi));
            const f16x2 h01 = __builtin_amdgcn_cvt_pkrtz(r0, r1);
            const f16x2 h23 = __builtin_amdgcn_cvt_pkrtz(r2, r3);
            const f16x4 bf = {h01.x, h01.y, h23.x, h23.y};
            acc[0][i] = __builtin_amdgcn_mfma_f32_16x16x16f16(af0, bf, acc[0][i], 0, 0, 0);
            acc[1][i] = __builtin_amdgcn_mfma_f32_16x16x16f16(af1, bf, acc[1][i], 0, 0, 0);
        }
    }

    // ---- Epilogue: D[row=quad*4+r][col=lhalf], point p = mt*16+quad*4+r ----
#pragma unroll
    for (int mt = 0; mt < 2; ++mt) {
        const float4 nrm4 = *(const float4*)&nrmtab[mt * 16 + quad * 4];
        const float iv[4] = { 1.f / (nrm4.x + 1e-11f), 1.f / (nrm4.y + 1e-11f),
                              1.f / (nrm4.z + 1e-11f), 1.f / (nrm4.w + 1e-11f) };
#pragma unroll
        for (int i = 0; i < 2; ++i) {
            const int z = (zq2 * 2 + i) * 16 + lhalf;
#pragma unroll
            for (int r = 0; r < 4; ++r) {
                const int p = mt * 16 + quad * 4 + r;
                const int x = xb + (p >> 2);
                const int y = yb + (p & 3);
                out[(((size_t)(b * L + x)) * L + y) * L + z] = acc[mt][i][r] * iv[r];
            }
        }
    }
}

} // namespace

extern "C" void kernel_launch(void* const* d_in, const int* in_sizes, int n_in,
                              void* d_out, int out_size, void* d_ws, size_t ws_size,
                              hipStream_t stream) {
    const float* image  = (const float*)d_in[0];
    const float* angles = (const float*)d_in[1];
    float* out = (float*)d_out;
    (void)in_sizes; (void)n_in; (void)out_size; (void)d_ws; (void)ws_size;

    dim3 grid(L / 4, L / 8);   // 32 x 16 = 512 blocks = exactly 2 per CU
    bp_kernel<<<grid, 512, 0, stream>>>(image, angles, out);
}

// Round 10
// 126.318 us; speedup vs baseline: 1.2107x; 1.1549x over previous
//
#include <hip/hip_runtime.h>

namespace {

constexpr int L           = 128;
constexpr int NANG        = 120;
constexpr int SLICE_BYTES = L * L * 4;   // 65536 = 1<<16
constexpr int ROW_BYTES   = L * 4;       // 512

typedef __fp16 f16x2 __attribute__((ext_vector_type(2)));
typedef __fp16 f16x4 __attribute__((ext_vector_type(4)));
typedef float  f32x4 __attribute__((ext_vector_type(4)));

// Block: 512 thr = 8 waves. Tile: 8(x) x 4(y) = 32 points, both b, all 128 z.
// Wave w: b = w&1, zq2 = w>>1 (32-z quarter); computes BOTH 16-point M-tiles.
// Direct-from-global B-fragments (L1/L2-hot), SGPR load bases (readfirstlane),
// manual 2-angle-pair software pipeline (depth 1) -- no barriers in main loop.
__global__ __launch_bounds__(512, 4) void bp_kernel(
    const float* __restrict__ image,   // [2,120,128,128] f32
    const float* __restrict__ angles,  // [120] deg
    float* __restrict__ out)           // [2,128,128,128] f32
{
    __shared__ alignas(16) uint2 wtab[NANG * 32];  // 30 KiB: [a][p] {w0|w1<<16, s0}
    __shared__ float2   acs[NANG];
    __shared__ unsigned arlo[NANG];                // per-angle first row (<= 116)
    __shared__ alignas(16) float nrmtab[32];

    const int tid = threadIdx.x;
    const int yb  = blockIdx.x * 4;
    const int xb  = blockIdx.y * 8;
    const float cx = (L - 1) * 0.5f;

    // ---- Phase 0: per-angle rotation params + tile row floor ----
    if (tid < NANG) {
        const float phi = -angles[tid] * 0.017453292519943295f;
        float s, c;
        sincosf(phi, &s, &c);
        const float X0 = (float)xb - cx,       X1 = (float)(xb + 7) - cx;
        const float Y0 = (float)yb - cx,       Y1 = (float)(yb + 3) - cx;
        const float a00 = -s * X0 + c * Y0 + cx;
        const float a01 = -s * X0 + c * Y1 + cx;
        const float a10 = -s * X1 + c * Y0 + cx;
        const float a11 = -s * X1 + c * Y1 + cx;
        const float symin = fminf(fminf(a00, a01), fminf(a10, a11));
        acs[tid]  = make_float2(c, s);
        // rlo <= 116 so rows rlo..rlo+11 are always in-bounds (window still
        // covers all nonzero-weight rows: span <= 12, rows <= 127).
        arlo[tid] = (unsigned)min(max((int)floorf(symin) - 1, 0), 116);
    }
    if (tid < 32) nrmtab[tid] = 0.f;
    __syncthreads();

    // ---- Phase 1: per-(point,angle) entry {f16 w0|w1, s0}; s1 == s0+1 implicit ----
    for (int e = tid; e < 32 * NANG; e += 512) {
        const int p = e / NANG;
        const int a = e - p * NANG;
        const float2 cs = acs[a];
        const int rlo = (int)arlo[a];
        const float X = (float)(xb + (p >> 2)) - cx;
        const float Y = (float)(yb + (p & 3)) - cx;
        const float sx =  cs.x * X + cs.y * Y + cx;
        const float sy = -cs.y * X + cs.x * Y + cx;
        const float x0f = floorf(sx), y0f = floorf(sy);
        const float wx = sx - x0f,    wy = sy - y0f;
        const int x0 = (int)x0f, y0 = (int)y0f;
        const float mx0 = (x0 >= 0  && x0 <  L)     ? 1.f : 0.f;
        const float mx1 = (x0 >= -1 && x0 <= L - 2) ? 1.f : 0.f;
        const float my0 = (y0 >= 0  && y0 <  L)     ? 1.f : 0.f;
        const float my1 = (y0 >= -1 && y0 <= L - 2) ? 1.f : 0.f;
        const float A   = (1.f - wx) * mx0 + wx * mx1;
        float w0f = (1.f - wy) * my0 * A;
        float w1f = wy * my1 * A;
        const int y0c = min(max(y0, 0), L - 1);
        const int y1c = min(max(y0 + 1, 0), L - 1);
        const int s0  = min(max(y0c - rlo, 0), 11);
        const int s1  = min(max(y1c - rlo, 0), 11);
        // Boundary clamp collision (s1==s0): fold w1 into w0 (exact: one mask is 0).
        // Guarantees nonzero weights only at k <= 11 (quad 3 is always A=0).
        if (s0 == s1) { w0f += w1f; w1f = 0.f; }
        f16x2 wh = __builtin_amdgcn_cvt_pkrtz(w0f, w1f);
        uint2 ent;
        ent.x = *reinterpret_cast<unsigned*>(&wh);
        ent.y = (unsigned)s0;
        wtab[a * 32 + p] = ent;
        atomicAdd(&nrmtab[p], w0f + w1f);
    }
    __syncthreads();   // the ONLY barrier before the epilogue

    const int wave  = tid >> 6;
    const int lane  = tid & 63;
    const int quad  = lane >> 4;
    const int lhalf = lane & 15;
    const int b     = wave & 1;
    const int zq2   = wave >> 1;               // 0..3, 32 z's each
    const char* __restrict__ imgc = (const char*)image;

    // Wave-uniform scalar slice base; per-lane 32-bit row/col offsets.
    const unsigned bbase_s = __builtin_amdgcn_readfirstlane((unsigned)(b * NANG) * SLICE_BYTES);
    const unsigned zoff0   = (unsigned)((zq2 * 2) * 16 + lhalf) * 4u;
    const int quad4 = (quad == 3) ? 0 : (quad * 4);   // quad3 re-reads quad0's rows (A=0 there)
    unsigned qz[4];
#pragma unroll
    for (int j = 0; j < 4; ++j) qz[j] = (unsigned)(quad4 + j) * ROW_BYTES + zoff0;

    f32x4 acc[2][2] = {};   // [mt][i]

    // A-fragment: nonzeros at k=s0 (w0), k=s0+1 (w1); element j of quad's 64-bit window.
    auto build_af = [&](uint2 e) -> f16x4 {
        const unsigned s0 = e.y;
        const unsigned t  = s0 & 3u;
        const int      q0 = (int)(s0 >> 2);
        const unsigned long long W = (unsigned long long)e.x << (t * 16u);
        const unsigned spill = (t == 3u) ? (e.x >> 16) : 0u;
        const unsigned long long af64 =
            (quad == q0) ? W : ((quad == q0 + 1) ? (unsigned long long)spill : 0ull);
        union { unsigned long long u; f16x4 v; } c; c.u = af64; return c.v;
    };

    // read tables for angle pair (a, a+1)
    auto read_tab = [&](int a, uint2* tA, uint2* tB, unsigned* rl) {
        tA[0] = wtab[a * 32 + lhalf];
        tB[0] = wtab[a * 32 + 16 + lhalf];
        tA[1] = wtab[(a + 1) * 32 + lhalf];
        tB[1] = wtab[(a + 1) * 32 + 16 + lhalf];
        rl[0] = __builtin_amdgcn_readfirstlane(arlo[a]);
        rl[1] = __builtin_amdgcn_readfirstlane(arlo[a + 1]);
    };
    // issue 16 loads for angle pair (a, a+1); r[16]: [angle*8 + j*2 + i]
    auto issue2 = [&](int a, const unsigned* rl, float* r) {
#pragma unroll
        for (int u = 0; u < 2; ++u) {
            const char* pa = imgc + (bbase_s + ((unsigned)(a + u) << 16) + (rl[u] << 9)); // SGPR base
#pragma unroll
            for (int j = 0; j < 4; ++j) {
                r[u * 8 + j * 2 + 0] = *(const float*)(pa + qz[j]);
                r[u * 8 + j * 2 + 1] = *(const float*)(pa + qz[j] + 64);  // imm offset
            }
        }
    };
    auto compute = [&](uint2 eA, uint2 eB, const float* r) {
        const f16x4 af0 = build_af(eA);
        const f16x4 af1 = build_af(eB);
#pragma unroll
        for (int i = 0; i < 2; ++i) {
            const f16x2 h01 = __builtin_amdgcn_cvt_pkrtz(r[0 + i], r[2 + i]);
            const f16x2 h23 = __builtin_amdgcn_cvt_pkrtz(r[4 + i], r[6 + i]);
            const f16x4 bf = {h01.x, h01.y, h23.x, h23.y};
            acc[0][i] = __builtin_amdgcn_mfma_f32_16x16x16f16(af0, bf, acc[0][i], 0, 0, 0);
            acc[1][i] = __builtin_amdgcn_mfma_f32_16x16x16f16(af1, bf, acc[1][i], 0, 0, 0);
        }
    };

    // ---- Main loop: hand-rolled 2-stage pipeline over angle pairs ----
    uint2 A0[2], B0[2], A1[2], B1[2];
    unsigned R0[2], R1[2];
    float r0buf[16], r1buf[16];

    read_tab(0, A0, B0, R0);
    issue2(0, R0, r0buf);

    for (int a = 0; a < NANG; a += 4) {
        if (a + 2 < NANG) { read_tab(a + 2, A1, B1, R1); issue2(a + 2, R1, r1buf); }
        compute(A0[0], B0[0], r0buf);
        compute(A0[1], B0[1], r0buf + 8);
        if (a + 4 < NANG) { read_tab(a + 4, A0, B0, R0); issue2(a + 4, R0, r0buf); }
        compute(A1[0], B1[0], r1buf);
        compute(A1[1], B1[1], r1buf + 8);
    }

    // ---- Epilogue: D[row=quad*4+r][col=lhalf], point p = mt*16+quad*4+r ----
#pragma unroll
    for (int mt = 0; mt < 2; ++mt) {
        const float4 nrm4 = *(const float4*)&nrmtab[mt * 16 + quad * 4];
        const float iv[4] = { 1.f / (nrm4.x + 1e-11f), 1.f / (nrm4.y + 1e-11f),
                              1.f / (nrm4.z + 1e-11f), 1.f / (nrm4.w + 1e-11f) };
#pragma unroll
        for (int i = 0; i < 2; ++i) {
            const int z = (zq2 * 2 + i) * 16 + lhalf;
#pragma unroll
            for (int r = 0; r < 4; ++r) {
                const int p = mt * 16 + quad * 4 + r;
                const int x = xb + (p >> 2);
                const int y = yb + (p & 3);
                out[(((size_t)(b * L + x)) * L + y) * L + z] = acc[mt][i][r] * iv[r];
            }
        }
    }
}

} // namespace

extern "C" void kernel_launch(void* const* d_in, const int* in_sizes, int n_in,
                              void* d_out, int out_size, void* d_ws, size_t ws_size,
                              hipStream_t stream) {
    const float* image  = (const float*)d_in[0];
    const float* angles = (const float*)d_in[1];
    float* out = (float*)d_out;
    (void)in_sizes; (void)n_in; (void)out_size; (void)d_ws; (void)ws_size;

    dim3 grid(L / 4, L / 8);   // 32 x 16 = 512 blocks = exactly 2 per CU
    bp_kernel<<<grid, 512, 0, stream>>>(image, angles, out);
}

// Round 11
// 124.705 us; speedup vs baseline: 1.2263x; 1.0129x over previous
//
#include <hip/hip_runtime.h>

namespace {

constexpr int L           = 128;
constexpr int NANG        = 120;
constexpr int SLICE_BYTES = L * L * 4;   // 65536 = 1<<16
constexpr int ROW_BYTES   = L * 4;       // 512

typedef __fp16 f16x2 __attribute__((ext_vector_type(2)));
typedef __fp16 f16x4 __attribute__((ext_vector_type(4)));
typedef float  f32x4 __attribute__((ext_vector_type(4)));

// Block: 512 thr = 8 waves. Tile: 8(x) x 4(y) = 32 points, both b, all 128 z.
// Wave w: b = w&1, zq2 = w>>1 (32-z quarter); computes BOTH 16-point M-tiles.
// Direct-from-global B-fragments (L1/L2-hot), SGPR load bases (readfirstlane),
// 3-buffer register pipeline prefetching 2 angle-pairs (4 angles) ahead --
// no barriers in the main loop.
__global__ __launch_bounds__(512, 4) void bp_kernel(
    const float* __restrict__ image,   // [2,120,128,128] f32
    const float* __restrict__ angles,  // [120] deg
    float* __restrict__ out)           // [2,128,128,128] f32
{
    __shared__ alignas(16) uint2 wtab[NANG * 32];  // 30 KiB: [a][p] {w0|w1<<16, s0}
    __shared__ float2   acs[NANG];
    __shared__ unsigned arlo[NANG];                // per-angle first row (<= 116)
    __shared__ alignas(16) float nrmtab[32];

    const int tid = threadIdx.x;
    const int yb  = blockIdx.x * 4;
    const int xb  = blockIdx.y * 8;
    const float cx = (L - 1) * 0.5f;

    // ---- Phase 0: per-angle rotation params + tile row floor ----
    if (tid < NANG) {
        const float phi = -angles[tid] * 0.017453292519943295f;
        float s, c;
        sincosf(phi, &s, &c);
        const float X0 = (float)xb - cx,       X1 = (float)(xb + 7) - cx;
        const float Y0 = (float)yb - cx,       Y1 = (float)(yb + 3) - cx;
        const float a00 = -s * X0 + c * Y0 + cx;
        const float a01 = -s * X0 + c * Y1 + cx;
        const float a10 = -s * X1 + c * Y0 + cx;
        const float a11 = -s * X1 + c * Y1 + cx;
        const float symin = fminf(fminf(a00, a01), fminf(a10, a11));
        acs[tid]  = make_float2(c, s);
        // rlo <= 116 so rows rlo..rlo+11 are always in-bounds (window still
        // covers all nonzero-weight rows: span <= 12, rows <= 127).
        arlo[tid] = (unsigned)min(max((int)floorf(symin) - 1, 0), 116);
    }
    if (tid < 32) nrmtab[tid] = 0.f;
    __syncthreads();

    // ---- Phase 1: per-(point,angle) entry {f16 w0|w1, s0}; s1 == s0+1 implicit ----
    for (int e = tid; e < 32 * NANG; e += 512) {
        const int p = e / NANG;
        const int a = e - p * NANG;
        const float2 cs = acs[a];
        const int rlo = (int)arlo[a];
        const float X = (float)(xb + (p >> 2)) - cx;
        const float Y = (float)(yb + (p & 3)) - cx;
        const float sx =  cs.x * X + cs.y * Y + cx;
        const float sy = -cs.y * X + cs.x * Y + cx;
        const float x0f = floorf(sx), y0f = floorf(sy);
        const float wx = sx - x0f,    wy = sy - y0f;
        const int x0 = (int)x0f, y0 = (int)y0f;
        const float mx0 = (x0 >= 0  && x0 <  L)     ? 1.f : 0.f;
        const float mx1 = (x0 >= -1 && x0 <= L - 2) ? 1.f : 0.f;
        const float my0 = (y0 >= 0  && y0 <  L)     ? 1.f : 0.f;
        const float my1 = (y0 >= -1 && y0 <= L - 2) ? 1.f : 0.f;
        const float A   = (1.f - wx) * mx0 + wx * mx1;
        float w0f = (1.f - wy) * my0 * A;
        float w1f = wy * my1 * A;
        const int y0c = min(max(y0, 0), L - 1);
        const int y1c = min(max(y0 + 1, 0), L - 1);
        const int s0  = min(max(y0c - rlo, 0), 11);
        const int s1  = min(max(y1c - rlo, 0), 11);
        // Boundary clamp collision (s1==s0): fold w1 into w0 (exact: one mask is 0).
        // Guarantees nonzero weights only at k <= 11 (quad 3 is always A=0).
        if (s0 == s1) { w0f += w1f; w1f = 0.f; }
        f16x2 wh = __builtin_amdgcn_cvt_pkrtz(w0f, w1f);
        uint2 ent;
        ent.x = *reinterpret_cast<unsigned*>(&wh);
        ent.y = (unsigned)s0;
        wtab[a * 32 + p] = ent;
        atomicAdd(&nrmtab[p], w0f + w1f);
    }
    __syncthreads();   // the ONLY barrier before the epilogue

    const int wave  = tid >> 6;
    const int lane  = tid & 63;
    const int quad  = lane >> 4;
    const int lhalf = lane & 15;
    const int b     = wave & 1;
    const int zq2   = wave >> 1;               // 0..3, 32 z's each
    const char* __restrict__ imgc = (const char*)image;

    // Wave-uniform scalar slice base; per-lane 32-bit row/col offsets.
    const unsigned bbase_s = __builtin_amdgcn_readfirstlane((unsigned)(b * NANG) * SLICE_BYTES);
    const unsigned zoff0   = (unsigned)((zq2 * 2) * 16 + lhalf) * 4u;
    const int quad4 = (quad == 3) ? 0 : (quad * 4);   // quad3 re-reads quad0's rows (A=0 there)
    unsigned qz[4];
#pragma unroll
    for (int j = 0; j < 4; ++j) qz[j] = (unsigned)(quad4 + j) * ROW_BYTES + zoff0;

    f32x4 acc[2][2] = {};   // [mt][i]

    // A-fragment: nonzeros at k=s0 (w0), k=s0+1 (w1); element j of quad's 64-bit window.
    auto build_af = [&](uint2 e) -> f16x4 {
        const unsigned s0 = e.y;
        const unsigned t  = s0 & 3u;
        const int      q0 = (int)(s0 >> 2);
        const unsigned long long W = (unsigned long long)e.x << (t * 16u);
        const unsigned spill = (t == 3u) ? (e.x >> 16) : 0u;
        const unsigned long long af64 =
            (quad == q0) ? W : ((quad == q0 + 1) ? (unsigned long long)spill : 0ull);
        union { unsigned long long u; f16x4 v; } c; c.u = af64; return c.v;
    };

    // read tables for angle pair p (angles 2p, 2p+1)
    auto read_tab = [&](int pr, uint2* tA, uint2* tB, unsigned* rl) {
        const int a = 2 * pr;
        tA[0] = wtab[a * 32 + lhalf];
        tB[0] = wtab[a * 32 + 16 + lhalf];
        tA[1] = wtab[(a + 1) * 32 + lhalf];
        tB[1] = wtab[(a + 1) * 32 + 16 + lhalf];
        rl[0] = __builtin_amdgcn_readfirstlane(arlo[a]);
        rl[1] = __builtin_amdgcn_readfirstlane(arlo[a + 1]);
    };
    // issue 16 loads for angle pair p; r[16]: [angle*8 + j*2 + i]
    auto issue2 = [&](int pr, const unsigned* rl, float* r) {
        const int a = 2 * pr;
#pragma unroll
        for (int u = 0; u < 2; ++u) {
            const char* pa = imgc + (bbase_s + ((unsigned)(a + u) << 16) + (rl[u] << 9)); // SGPR base
#pragma unroll
            for (int j = 0; j < 4; ++j) {
                r[u * 8 + j * 2 + 0] = *(const float*)(pa + qz[j]);
                r[u * 8 + j * 2 + 1] = *(const float*)(pa + qz[j] + 64);  // imm offset
            }
        }
    };
    auto compute = [&](uint2 eA, uint2 eB, const float* r) {
        const f16x4 af0 = build_af(eA);
        const f16x4 af1 = build_af(eB);
#pragma unroll
        for (int i = 0; i < 2; ++i) {
            const f16x2 h01 = __builtin_amdgcn_cvt_pkrtz(r[0 + i], r[2 + i]);
            const f16x2 h23 = __builtin_amdgcn_cvt_pkrtz(r[4 + i], r[6 + i]);
            const f16x4 bf = {h01.x, h01.y, h23.x, h23.y};
            acc[0][i] = __builtin_amdgcn_mfma_f32_16x16x16f16(af0, bf, acc[0][i], 0, 0, 0);
            acc[1][i] = __builtin_amdgcn_mfma_f32_16x16x16f16(af1, bf, acc[1][i], 0, 0, 0);
        }
    };

    // ---- Main loop: 3-buffer pipeline over 60 angle-pairs, prefetch depth 2 ----
    uint2 A0[2], B0[2], A1[2], B1[2], A2[2], B2[2];
    unsigned R0[2], R1[2], R2[2];
    float rb0[16], rb1[16], rb2[16];

    read_tab(0, A0, B0, R0); issue2(0, R0, rb0);
    read_tab(1, A1, B1, R1); issue2(1, R1, rb1);

    for (int p = 0; p < 60; p += 3) {
        if (p + 2 < 60) { read_tab(p + 2, A2, B2, R2); issue2(p + 2, R2, rb2); }
        compute(A0[0], B0[0], rb0);
        compute(A0[1], B0[1], rb0 + 8);
        if (p + 3 < 60) { read_tab(p + 3, A0, B0, R0); issue2(p + 3, R0, rb0); }
        compute(A1[0], B1[0], rb1);
        compute(A1[1], B1[1], rb1 + 8);
        if (p + 4 < 60) { read_tab(p + 4, A1, B1, R1); issue2(p + 4, R1, rb1); }
        compute(A2[0], B2[0], rb2);
        compute(A2[1], B2[1], rb2 + 8);
    }

    // ---- Epilogue: D[row=quad*4+r][col=lhalf], point p = mt*16+quad*4+r ----
#pragma unroll
    for (int mt = 0; mt < 2; ++mt) {
        const float4 nrm4 = *(const float4*)&nrmtab[mt * 16 + quad * 4];
        const float iv[4] = { 1.f / (nrm4.x + 1e-11f), 1.f / (nrm4.y + 1e-11f),
                              1.f / (nrm4.z + 1e-11f), 1.f / (nrm4.w + 1e-11f) };
#pragma unroll
        for (int i = 0; i < 2; ++i) {
            const int z = (zq2 * 2 + i) * 16 + lhalf;
#pragma unroll
            for (int r = 0; r < 4; ++r) {
                const int p = mt * 16 + quad * 4 + r;
                const int x = xb + (p >> 2);
                const int y = yb + (p & 3);
                out[(((size_t)(b * L + x)) * L + y) * L + z] = acc[mt][i][r] * iv[r];
            }
        }
    }
}

} // namespace

extern "C" void kernel_launch(void* const* d_in, const int* in_sizes, int n_in,
                              void* d_out, int out_size, void* d_ws, size_t ws_size,
                              hipStream_t stream) {
    const float* image  = (const float*)d_in[0];
    const float* angles = (const float*)d_in[1];
    float* out = (float*)d_out;
    (void)in_sizes; (void)n_in; (void)out_size; (void)d_ws; (void)ws_size;

    dim3 grid(L / 4, L / 8);   // 32 x 16 = 512 blocks = exactly 2 per CU
    bp_kernel<<<grid, 512, 0, stream>>>(image, angles, out);
}